// Round 6
// baseline (250.011 us; speedup 1.0000x reference)
//
#include <hip/hip_runtime.h>
#include <hip/hip_bf16.h>

typedef __attribute__((ext_vector_type(8))) short short8;
typedef __attribute__((ext_vector_type(4))) short short4v;
typedef __attribute__((ext_vector_type(4))) float float4v;

#define MFMA16(a, b, c) __builtin_amdgcn_mfma_f32_16x16x32_bf16((a), (b), (c), 0, 0, 0)
// source-level fence only: HW DS pipe is in-order per wave; compiler emits precise lgkmcnt
#define LDS_FENCE() asm volatile("" ::: "memory")

constexpr int kN = 512;
constexpr int kD = 64;
constexpr int kThreads = 512;  // 8 waves, 2/SIMD -> 256 VGPR/wave budget (no spills)

// LDS layout (ushort elements):
//   [0,      32768)  K swizzled bf16 (B-operand for QK^T, channel-contiguous):
//                      elem (n,d) at (d>>3)*4096 + n*8 + (d&7)
//   [32768,  65536)  V swizzled bf16 (B-operand for PV, POSITION-contiguous):
//                      elem (n,d) at (n>>3)*512 + d*8 + (n&7)
//   [65536,  69632)  Wdsw: Wv staging during phase 1; Wd (B-swizzle) in phase 2/3
//   [69632,  79872)  rep: Wq (0..4096) + Wk (4096..8192) staging during phase 1;
//                    reused as 8 waves x 2 slots x (16 rows x 40) repack buffers
constexpr int LDS_TOTAL_BYTES = 79872 * 2;  // 156 KiB -> 1 block/CU

static __device__ __forceinline__ unsigned short f2bf(float f) {
  unsigned int u = __float_as_uint(f);
  u = (u + 0x7fffu + ((u >> 16) & 1u)) >> 16;
  return (unsigned short)u;
}

static __device__ __forceinline__ unsigned int f2bf2(float a, float b) {
  union {
    __hip_bfloat162 h;
    unsigned int u;
  } cvt;
  cvt.h = __float22bfloat162_rn(float2{a, b});
  return cvt.u;  // low16 = a, high16 = b
}

union S8U4 {
  short8 s8;
  unsigned int u4[4];
};

__global__ __launch_bounds__(kThreads, 2) void ts_attn_fused(
    const float* __restrict__ x, const float* __restrict__ Wq_t,
    const float* __restrict__ Wk_t, const float* __restrict__ Wv_t,
    const float* __restrict__ Wq_s, const float* __restrict__ Wk_s,
    const float* __restrict__ Wv_s, const float* __restrict__ Wd_t,
    const float* __restrict__ bd_t, const float* __restrict__ Wd_s,
    const float* __restrict__ bd_s, float* __restrict__ out) {
  extern __shared__ __align__(16) unsigned short smem_us[];
  unsigned short* Ksw = smem_us;           // 32768 elems
  unsigned short* Vsw = smem_us + 32768;   // 32768 elems
  unsigned short* Wdsw = smem_us + 65536;  // 4096 elems
  unsigned short* rep = smem_us + 69632;   // 10240 elems

  const int tid = threadIdx.x;
  const int wv = tid >> 6;   // wave 0..7
  const int lane = tid & 63;
  const int ln = lane & 15;
  const int quad = lane >> 4;
  const int b = blockIdx.x;

  const float* xb = x + (size_t)b * (kN * kD);
  float* outb = out + (size_t)b * (kN * kD);

  // weight staging indices: thread covers (d, e0..e0+7)
  const int sd = tid >> 3;         // 0..63
  const int se0 = (tid & 7) * 8;   // 0..56
  const int sbase = (sd >> 3) * 512 + (sd & 7);

  float bdsum[4];
#pragma unroll
  for (int nt = 0; nt < 4; ++nt) bdsum[nt] = bd_t[nt * 16 + ln] + bd_s[nt * 16 + ln];

  unsigned short* slot0 = rep + wv * 1280;  // 16 x 40 repack slot A (wave-local)
  unsigned short* slot1 = slot0 + 640;      // slot B

#pragma unroll 1
  for (int br = 0; br < 2; ++br) {
    const float* Wq = br ? Wq_s : Wq_t;
    const float* Wk = br ? Wk_s : Wk_t;
    const float* Wv = br ? Wv_s : Wv_t;
    const float* Wd = br ? Wd_s : Wd_t;

    // ---- stage Wq, Wk, Wv into LDS (bf16, B-operand swizzle) ----
    {
      const float* srcs[3] = {Wq, Wk, Wv};
      unsigned short* dsts[3] = {rep, rep + 4096, Wdsw};
#pragma unroll
      for (int g = 0; g < 3; ++g) {
        const float4v u0 = *reinterpret_cast<const float4v*>(srcs[g] + sd * 64 + se0);
        const float4v u1 = *reinterpret_cast<const float4v*>(srcs[g] + sd * 64 + se0 + 4);
        unsigned short* dst = dsts[g];
#pragma unroll
        for (int i = 0; i < 4; ++i) dst[sbase + (se0 + i) * 8] = f2bf(u0[i]);
#pragma unroll
        for (int i = 0; i < 4; ++i) dst[sbase + (se0 + 4 + i) * 8] = f2bf(u1[i]);
      }
    }

    // ---- x A-frags for this wave's 4 m-tiles (global, L3-resident 2nd branch) ----
    short8 xa[4][2];
#pragma unroll
    for (int mi = 0; mi < 4; ++mi) {
      const int mrow = (wv + mi * 8) * 16 + ln;
      const float4v u0 = *reinterpret_cast<const float4v*>(xb + mrow * 64 + quad * 8);
      const float4v v0 = *reinterpret_cast<const float4v*>(xb + mrow * 64 + quad * 8 + 4);
      const float4v u1 = *reinterpret_cast<const float4v*>(xb + mrow * 64 + 32 + quad * 8);
      const float4v v1 = *reinterpret_cast<const float4v*>(xb + mrow * 64 + 32 + quad * 8 + 4);
      S8U4 t0, t1;
      t0.u4[0] = f2bf2(u0[0], u0[1]);
      t0.u4[1] = f2bf2(u0[2], u0[3]);
      t0.u4[2] = f2bf2(v0[0], v0[1]);
      t0.u4[3] = f2bf2(v0[2], v0[3]);
      t1.u4[0] = f2bf2(u1[0], u1[1]);
      t1.u4[1] = f2bf2(u1[2], u1[3]);
      t1.u4[2] = f2bf2(v1[0], v1[1]);
      t1.u4[3] = f2bf2(v1[2], v1[3]);
      xa[mi][0] = t0.s8;
      xa[mi][1] = t1.s8;
    }
    __syncthreads();

    // ---- phase 1: Q,K,V = X @ W; each weight-frag read feeds 4 m-tiles ----
    short4v qd[4][4];  // Q D-frags bf16-packed
#pragma unroll
    for (int g = 0; g < 3; ++g) {
      const unsigned short* Wl = (g == 0) ? rep : (g == 1) ? (rep + 4096) : Wdsw;
#pragma unroll
      for (int nt = 0; nt < 4; ++nt) {
        const short8 b0 = *reinterpret_cast<const short8*>(Wl + quad * 512 + (nt * 16 + ln) * 8);
        const short8 b1 =
            *reinterpret_cast<const short8*>(Wl + (4 + quad) * 512 + (nt * 16 + ln) * 8);
#pragma unroll
        for (int mi = 0; mi < 4; ++mi) {
          const int mt = wv + mi * 8;
          float4v acc = {0.f, 0.f, 0.f, 0.f};
          acc = MFMA16(xa[mi][0], b0, acc);
          acc = MFMA16(xa[mi][1], b1, acc);
          // D-frag: element (row = mt*16 + quad*4 + r, col e = nt*16 + ln)
          if (g == 0) {
            short4v pk;
#pragma unroll
            for (int r = 0; r < 4; ++r) pk[r] = (short)f2bf(acc[r]);
            qd[mi][nt] = pk;
          } else if (g == 1) {
            const int ehi = nt * 2 + (ln >> 3);
            const int elo = ln & 7;
#pragma unroll
            for (int r = 0; r < 4; ++r)
              Ksw[ehi * 4096 + (mt * 16 + quad * 4 + r) * 8 + elo] = f2bf(acc[r]);
          } else {
            short4v pk;
#pragma unroll
            for (int r = 0; r < 4; ++r) pk[r] = (short)f2bf(acc[r]);
            const int vbase = (mt * 2 + (quad >> 1)) * 512 + (nt * 16 + ln) * 8 + (quad & 1) * 4;
            *reinterpret_cast<short4v*>(Vsw + vbase) = pk;
          }
        }
      }
    }
    __syncthreads();

    // ---- stage Wd (overwrites Wv staging; V already built) ----
    {
      const float4v u0 = *reinterpret_cast<const float4v*>(Wd + sd * 64 + se0);
      const float4v u1 = *reinterpret_cast<const float4v*>(Wd + sd * 64 + se0 + 4);
#pragma unroll
      for (int i = 0; i < 4; ++i) Wdsw[sbase + (se0 + i) * 8] = f2bf(u0[i]);
#pragma unroll
      for (int i = 0; i < 4; ++i) Wdsw[sbase + (se0 + 4 + i) * 8] = f2bf(u1[i]);
    }
    __syncthreads();

    // ---- phase 2/3: all 4 Q-tiles per wave in ONE K/V sweep (4x frag reuse) ----
    // Q D-frag -> A-frag repack, two slots per tile -> one fence per tile
    short8 q[4][2];
#pragma unroll
    for (int u = 0; u < 4; ++u) {
#pragma unroll
      for (int r = 0; r < 4; ++r) {
        slot0[(quad * 4 + r) * 40 + ln] = (unsigned short)qd[u][0][r];
        slot0[(quad * 4 + r) * 40 + 16 + ln] = (unsigned short)qd[u][1][r];
        slot1[(quad * 4 + r) * 40 + ln] = (unsigned short)qd[u][2][r];
        slot1[(quad * 4 + r) * 40 + 16 + ln] = (unsigned short)qd[u][3][r];
      }
      LDS_FENCE();
      q[u][0] = *reinterpret_cast<const short8*>(slot0 + ln * 40 + quad * 8);
      q[u][1] = *reinterpret_cast<const short8*>(slot1 + ln * 40 + quad * 8);
      LDS_FENCE();
    }

    float sum[4][4];
    float4v o[4][4];
#pragma unroll
    for (int u = 0; u < 4; ++u)
#pragma unroll
      for (int i = 0; i < 4; ++i) {
        sum[u][i] = 0.f;
        o[u][i] = (float4v){0.f, 0.f, 0.f, 0.f};
      }

#pragma unroll 1
    for (int kcg = 0; kcg < 16; ++kcg) {
      // QK: 4 K-frag reads -> 16 MFMAs
      float4v s[4][2];
#pragma unroll
      for (int h = 0; h < 2; ++h) {
        const int nt = kcg * 2 + h;
        const short8 k0 = *reinterpret_cast<const short8*>(Ksw + quad * 4096 + (nt * 16 + ln) * 8);
        const short8 k1 =
            *reinterpret_cast<const short8*>(Ksw + (4 + quad) * 4096 + (nt * 16 + ln) * 8);
#pragma unroll
        for (int u = 0; u < 4; ++u) {
          float4v acc = {0.f, 0.f, 0.f, 0.f};
          acc = MFMA16(q[u][0], k0, acc);
          acc = MFMA16(q[u][1], k1, acc);
          s[u][h] = acc;
        }
      }

      // exp + pack u0,u1 into the two slots
#pragma unroll
      for (int u = 0; u < 2; ++u) {
        unsigned short* sl = u ? slot1 : slot0;
#pragma unroll
        for (int h = 0; h < 2; ++h)
#pragma unroll
          for (int r = 0; r < 4; ++r) {
            const float p = __expf(s[u][h][r] * 0.125f);  // no max-shift: |s|<~10, fp32-safe
            sum[u][r] += p;
            sl[(quad * 4 + r) * 40 + h * 16 + ln] = f2bf(p);
          }
      }
      LDS_FENCE();
      const short8 pa0 = *reinterpret_cast<const short8*>(slot0 + ln * 40 + quad * 8);
      const short8 pa1 = *reinterpret_cast<const short8*>(slot1 + ln * 40 + quad * 8);
      // V-frags read ONCE per kcg, reused by all 4 Q-tiles
      short8 vf[4];
#pragma unroll
      for (int nto = 0; nto < 4; ++nto)
        vf[nto] =
            *reinterpret_cast<const short8*>(Vsw + (kcg * 4 + quad) * 512 + (nto * 16 + ln) * 8);
#pragma unroll
      for (int nto = 0; nto < 4; ++nto) {
        o[0][nto] = MFMA16(pa0, vf[nto], o[0][nto]);
        o[1][nto] = MFMA16(pa1, vf[nto], o[1][nto]);
      }
      LDS_FENCE();  // pa0/pa1 reads precede slot reuse (in-order DS)

      // exp + pack u2,u3
#pragma unroll
      for (int u = 2; u < 4; ++u) {
        unsigned short* sl = (u == 3) ? slot1 : slot0;
#pragma unroll
        for (int h = 0; h < 2; ++h)
#pragma unroll
          for (int r = 0; r < 4; ++r) {
            const float p = __expf(s[u][h][r] * 0.125f);
            sum[u][r] += p;
            sl[(quad * 4 + r) * 40 + h * 16 + ln] = f2bf(p);
          }
      }
      LDS_FENCE();
      const short8 pa2 = *reinterpret_cast<const short8*>(slot0 + ln * 40 + quad * 8);
      const short8 pa3 = *reinterpret_cast<const short8*>(slot1 + ln * 40 + quad * 8);
#pragma unroll
      for (int nto = 0; nto < 4; ++nto) {
        o[2][nto] = MFMA16(pa2, vf[nto], o[2][nto]);
        o[3][nto] = MFMA16(pa3, vf[nto], o[3][nto]);
      }
      LDS_FENCE();
    }

    // row sums -> 1/sum
#pragma unroll
    for (int dd = 1; dd < 16; dd <<= 1)
#pragma unroll
      for (int u = 0; u < 4; ++u)
#pragma unroll
        for (int r = 0; r < 4; ++r) sum[u][r] += __shfl_xor(sum[u][r], dd, 64);
    float inv[4][4];
#pragma unroll
    for (int u = 0; u < 4; ++u)
#pragma unroll
      for (int r = 0; r < 4; ++r) inv[u][r] = 1.0f / sum[u][r];

    // O -> A-layout via the two slots (one fence per tile)
    short8 a[4][2];
#pragma unroll
    for (int u = 0; u < 4; ++u) {
#pragma unroll
      for (int r = 0; r < 4; ++r) {
        slot0[(quad * 4 + r) * 40 + ln] = f2bf(o[u][0][r] * inv[u][r]);
        slot0[(quad * 4 + r) * 40 + 16 + ln] = f2bf(o[u][1][r] * inv[u][r]);
        slot1[(quad * 4 + r) * 40 + ln] = f2bf(o[u][2][r] * inv[u][r]);
        slot1[(quad * 4 + r) * 40 + 16 + ln] = f2bf(o[u][3][r] * inv[u][r]);
      }
      LDS_FENCE();
      a[u][0] = *reinterpret_cast<const short8*>(slot0 + ln * 40 + quad * 8);
      a[u][1] = *reinterpret_cast<const short8*>(slot1 + ln * 40 + quad * 8);
      LDS_FENCE();
    }

    // dense: O @ Wd, each Wd-frag read feeds 4 tiles; br0 parks, br1 fused epilogue
#pragma unroll
    for (int nt = 0; nt < 4; ++nt) {
      const short8 w0 = *reinterpret_cast<const short8*>(Wdsw + quad * 512 + (nt * 16 + ln) * 8);
      const short8 w1 =
          *reinterpret_cast<const short8*>(Wdsw + (4 + quad) * 512 + (nt * 16 + ln) * 8);
      const int col = nt * 16 + ln;
#pragma unroll
      for (int u = 0; u < 4; ++u) {
        float4v d4 = {0.f, 0.f, 0.f, 0.f};
        d4 = MFMA16(a[u][0], w0, d4);
        d4 = MFMA16(a[u][1], w1, d4);
        const int m0 = (wv + u * 8) * 16 + quad * 4;
        if (br == 0) {
#pragma unroll
          for (int r = 0; r < 4; ++r) outb[(m0 + r) * 64 + col] = d4[r];
        } else {
#pragma unroll
          for (int r = 0; r < 4; ++r) {
            const float z = outb[(m0 + r) * 64 + col] + d4[r] + bdsum[nt];
            const float gate = 1.0f / (1.0f + __expf(-z));
            outb[(m0 + r) * 64 + col] = xb[(m0 + r) * 64 + col] * gate;
          }
        }
      }
    }
    __syncthreads();  // protect LDS before next branch restages
  }
}

extern "C" void kernel_launch(void* const* d_in, const int* in_sizes, int n_in,
                              void* d_out, int out_size, void* d_ws, size_t ws_size,
                              hipStream_t stream) {
  const float* x = (const float*)d_in[0];
  const float* Wq_t = (const float*)d_in[1];
  const float* Wk_t = (const float*)d_in[2];
  const float* Wv_t = (const float*)d_in[3];
  const float* Wq_s = (const float*)d_in[4];
  const float* Wk_s = (const float*)d_in[5];
  const float* Wv_s = (const float*)d_in[6];
  const float* Wd_t = (const float*)d_in[7];
  const float* bd_t = (const float*)d_in[8];
  const float* Wd_s = (const float*)d_in[9];
  const float* bd_s = (const float*)d_in[10];
  float* out = (float*)d_out;

  hipFuncSetAttribute(reinterpret_cast<const void*>(ts_attn_fused),
                      hipFuncAttributeMaxDynamicSharedMemorySize, LDS_TOTAL_BYTES);
  ts_attn_fused<<<dim3(256), dim3(kThreads), LDS_TOTAL_BYTES, stream>>>(
      x, Wq_t, Wk_t, Wv_t, Wq_s, Wk_s, Wv_s, Wd_t, bd_t, Wd_s, bd_s, out);
}

// Round 7
// 216.078 us; speedup vs baseline: 1.1570x; 1.1570x over previous
//
#include <hip/hip_runtime.h>
#include <hip/hip_bf16.h>

typedef __attribute__((ext_vector_type(8))) short short8;
typedef __attribute__((ext_vector_type(4))) short short4v;
typedef __attribute__((ext_vector_type(4))) float float4v;

#define MFMA16(a, b, c) __builtin_amdgcn_mfma_f32_16x16x32_bf16((a), (b), (c), 0, 0, 0)
// source-level fence only: HW DS pipe is in-order per wave; compiler emits precise lgkmcnt
#define LDS_FENCE() asm volatile("" ::: "memory")

constexpr int kN = 512;
constexpr int kD = 64;
constexpr int kThreads = 512;  // 8 waves, 2/SIMD -> 256 unified regs/wave (pinned below)

// LDS layout (ushort elements), 160 KiB total -> 1 block/CU:
//   [0,      32768)  K swizzled bf16 (B-operand for QK^T): (n,d) at (d>>3)*4096 + n*8 + (d&7)
//   [32768,  65536)  V swizzled bf16 (B-operand for PV):   (n,d) at (n>>3)*512 + d*8 + (n&7)
//   [65536,  69632)  Wd swizzled bf16: (d,e) at (d>>3)*512 + e*8 + (d&7)
//   [69632,  81920)  R: Wq/Wk/Wv staging (3*4096) during phase 1;
//                    phase 2: 8 waves x 2 slots x (16 rows x 40) repack buffers (10240 used)
constexpr int LDS_TOTAL_BYTES = 163840;

static __device__ __forceinline__ unsigned short f2bf(float f) {
  unsigned int u = __float_as_uint(f);
  u = (u + 0x7fffu + ((u >> 16) & 1u)) >> 16;
  return (unsigned short)u;
}

static __device__ __forceinline__ unsigned int f2bf2(float a, float b) {
  union {
    __hip_bfloat162 h;
    unsigned int u;
  } cvt;
  cvt.h = __float22bfloat162_rn(float2{a, b});
  return cvt.u;  // low16 = a, high16 = b
}

union S8U4 {
  short8 s8;
  unsigned int u4[4];
};

constexpr float kScLog2e = 0.125f * 1.44269504088896341f;  // score scale folded with log2(e)
constexpr float kLog2e = 1.44269504088896341f;

__global__ __launch_bounds__(kThreads) __attribute__((amdgpu_waves_per_eu(2, 2))) void
ts_attn_fused(const float* __restrict__ x, const float* __restrict__ Wq_t,
              const float* __restrict__ Wk_t, const float* __restrict__ Wv_t,
              const float* __restrict__ Wq_s, const float* __restrict__ Wk_s,
              const float* __restrict__ Wv_s, const float* __restrict__ Wd_t,
              const float* __restrict__ bd_t, const float* __restrict__ Wd_s,
              const float* __restrict__ bd_s, float* __restrict__ out) {
  extern __shared__ __align__(16) unsigned short smem_us[];
  unsigned short* Ksw = smem_us;           // 32768 elems
  unsigned short* Vsw = smem_us + 32768;   // 32768 elems
  unsigned short* Wdsw = smem_us + 65536;  // 4096 elems
  unsigned short* R = smem_us + 69632;     // 12288 elems

  const int tid = threadIdx.x;
  const int wv = tid >> 6;  // wave 0..7
  const int lane = tid & 63;
  const int ln = lane & 15;
  const int quad = lane >> 4;
  const int b = blockIdx.x;

  const float* xb = x + (size_t)b * (kN * kD);
  float* outb = out + (size_t)b * (kN * kD);

  // weight staging indices: thread covers (d, e0..e0+7)
  const int sd = tid >> 3;        // 0..63
  const int se0 = (tid & 7) * 8;  // 0..56
  const int sbase = (sd >> 3) * 512 + (sd & 7);

  float bdsum[4];
#pragma unroll
  for (int nt = 0; nt < 4; ++nt) bdsum[nt] = bd_t[nt * 16 + ln] + bd_s[nt * 16 + ln];

  // ---- load + convert x A-frags ONCE for both branches (4 m-tiles per wave) ----
  short8 xa[4][2];
#pragma unroll
  for (int mi = 0; mi < 4; ++mi) {
    const int mrow = (wv + mi * 8) * 16 + ln;
    const float4v u0 = *reinterpret_cast<const float4v*>(xb + mrow * 64 + quad * 8);
    const float4v v0 = *reinterpret_cast<const float4v*>(xb + mrow * 64 + quad * 8 + 4);
    const float4v u1 = *reinterpret_cast<const float4v*>(xb + mrow * 64 + 32 + quad * 8);
    const float4v v1 = *reinterpret_cast<const float4v*>(xb + mrow * 64 + 32 + quad * 8 + 4);
    S8U4 t0, t1;
    t0.u4[0] = f2bf2(u0[0], u0[1]);
    t0.u4[1] = f2bf2(u0[2], u0[3]);
    t0.u4[2] = f2bf2(v0[0], v0[1]);
    t0.u4[3] = f2bf2(v0[2], v0[3]);
    t1.u4[0] = f2bf2(u1[0], u1[1]);
    t1.u4[1] = f2bf2(u1[2], u1[3]);
    t1.u4[2] = f2bf2(v1[0], v1[1]);
    t1.u4[3] = f2bf2(v1[2], v1[3]);
    xa[mi][0] = t0.s8;
    xa[mi][1] = t1.s8;
  }

  unsigned short* slot0 = R + wv * 1280;  // 16 x 40 repack slot A (wave-local)
  unsigned short* slot1 = slot0 + 640;    // slot B

#pragma unroll 1
  for (int br = 0; br < 2; ++br) {
    const float* Wq = br ? Wq_s : Wq_t;
    const float* Wk = br ? Wk_s : Wk_t;
    const float* Wv = br ? Wv_s : Wv_t;
    const float* Wd = br ? Wd_s : Wd_t;

    // ---- stage Wq, Wk, Wv, Wd into LDS (bf16, B-operand swizzle), one sync ----
    {
      const float* srcs[4] = {Wq, Wk, Wv, Wd};
      unsigned short* dsts[4] = {R, R + 4096, R + 8192, Wdsw};
#pragma unroll
      for (int g = 0; g < 4; ++g) {
        const float4v u0 = *reinterpret_cast<const float4v*>(srcs[g] + sd * 64 + se0);
        const float4v u1 = *reinterpret_cast<const float4v*>(srcs[g] + sd * 64 + se0 + 4);
        unsigned short* dst = dsts[g];
#pragma unroll
        for (int i = 0; i < 4; ++i) dst[sbase + (se0 + i) * 8] = f2bf(u0[i]);
#pragma unroll
        for (int i = 0; i < 4; ++i) dst[sbase + (se0 + 4 + i) * 8] = f2bf(u1[i]);
      }
    }
    __syncthreads();

    // ---- phase 1: Q,K,V = X @ W; Q D-frags -> regs, K/V -> LDS ----
    short4v qd[4][4];  // qd[mi][nt][r] = bf16 Q[(wv+mi*8)*16+quad*4+r][nt*16+ln]
#pragma unroll
    for (int g = 0; g < 3; ++g) {
      const unsigned short* Wl = R + g * 4096;
#pragma unroll
      for (int nt = 0; nt < 4; ++nt) {
        const short8 b0 = *reinterpret_cast<const short8*>(Wl + quad * 512 + (nt * 16 + ln) * 8);
        const short8 b1 =
            *reinterpret_cast<const short8*>(Wl + (4 + quad) * 512 + (nt * 16 + ln) * 8);
#pragma unroll
        for (int mi = 0; mi < 4; ++mi) {
          const int mt = wv + mi * 8;
          float4v acc = {0.f, 0.f, 0.f, 0.f};
          acc = MFMA16(xa[mi][0], b0, acc);
          acc = MFMA16(xa[mi][1], b1, acc);
          if (g == 0) {
            short4v pk;
#pragma unroll
            for (int r = 0; r < 4; ++r) pk[r] = (short)f2bf(acc[r]);
            qd[mi][nt] = pk;
          } else if (g == 1) {
            const int ehi = nt * 2 + (ln >> 3);
            const int elo = ln & 7;
#pragma unroll
            for (int r = 0; r < 4; ++r)
              Ksw[ehi * 4096 + (mt * 16 + quad * 4 + r) * 8 + elo] = f2bf(acc[r]);
          } else {
            short4v pk;
#pragma unroll
            for (int r = 0; r < 4; ++r) pk[r] = (short)f2bf(acc[r]);
            const int vbase = (mt * 2 + (quad >> 1)) * 512 + (nt * 16 + ln) * 8 + (quad & 1) * 4;
            *reinterpret_cast<short4v*>(Vsw + vbase) = pk;
          }
        }
      }
    }
    __syncthreads();

    // ---- phase 2/3: per-wave Q-tiles (R2 skeleton) ----
#pragma unroll 1
    for (int qi = 0; qi < 4; ++qi) {
      const int qt = wv + qi * 8;

      // Q D-frag -> A-frag repack via two slots (one fence)
#pragma unroll
      for (int r = 0; r < 4; ++r) {
        slot0[(quad * 4 + r) * 40 + ln] = (unsigned short)qd[qi][0][r];
        slot0[(quad * 4 + r) * 40 + 16 + ln] = (unsigned short)qd[qi][1][r];
        slot1[(quad * 4 + r) * 40 + ln] = (unsigned short)qd[qi][2][r];
        slot1[(quad * 4 + r) * 40 + 16 + ln] = (unsigned short)qd[qi][3][r];
      }
      LDS_FENCE();
      const short8 q0 = *reinterpret_cast<const short8*>(slot0 + ln * 40 + quad * 8);
      const short8 q1 = *reinterpret_cast<const short8*>(slot1 + ln * 40 + quad * 8);
      LDS_FENCE();

      float sum[4] = {0.f, 0.f, 0.f, 0.f};
      float4v o[4];
#pragma unroll
      for (int i = 0; i < 4; ++i) o[i] = (float4v){0.f, 0.f, 0.f, 0.f};

      // two halves of 16 score tiles: 32 back-to-back MFMAs, then 8 kc of exp/pack/PV
#pragma unroll 1
      for (int h2 = 0; h2 < 2; ++h2) {
        float4v s[16];
#pragma unroll
        for (int t = 0; t < 16; ++t) {
          const int nt = h2 * 16 + t;
          const short8 k0 =
              *reinterpret_cast<const short8*>(Ksw + quad * 4096 + (nt * 16 + ln) * 8);
          const short8 k1 =
              *reinterpret_cast<const short8*>(Ksw + (4 + quad) * 4096 + (nt * 16 + ln) * 8);
          float4v acc = {0.f, 0.f, 0.f, 0.f};
          acc = MFMA16(q0, k0, acc);
          acc = MFMA16(q1, k1, acc);
          s[t] = acc;
        }
#pragma unroll
        for (int kc = 0; kc < 8; ++kc) {
          const int kcg = h2 * 8 + kc;
          unsigned short* slA = (kc & 1) ? slot1 : slot0;  // double-buffer alternation
#pragma unroll
          for (int t2 = 0; t2 < 2; ++t2) {
            const float4v sv = s[kc * 2 + t2];
#pragma unroll
            for (int r = 0; r < 4; ++r) {
              // no max-shift: |s|<~10 -> exp in fp32 is safe; single v_exp_f32
              const float p = __builtin_amdgcn_exp2f(sv[r] * kScLog2e);
              sum[r] += p;
              slA[(quad * 4 + r) * 40 + t2 * 16 + ln] = f2bf(p);
            }
          }
          LDS_FENCE();
          const short8 pa = *reinterpret_cast<const short8*>(slA + ln * 40 + quad * 8);
          LDS_FENCE();
#pragma unroll
          for (int nto = 0; nto < 4; ++nto) {
            const short8 vf = *reinterpret_cast<const short8*>(Vsw + (kcg * 4 + quad) * 512 +
                                                              (nto * 16 + ln) * 8);
            o[nto] = MFMA16(pa, vf, o[nto]);
          }
        }
      }

      // row sums (within the quad's 16 lanes) -> 1/sum
#pragma unroll
      for (int dd = 1; dd < 16; dd <<= 1)
#pragma unroll
        for (int r = 0; r < 4; ++r) sum[r] += __shfl_xor(sum[r], dd, 64);
      float inv[4];
#pragma unroll
      for (int r = 0; r < 4; ++r) inv[r] = __builtin_amdgcn_rcpf(sum[r]);

      // O (16x64) -> A-layout via the two slots (one fence)
#pragma unroll
      for (int r = 0; r < 4; ++r) {
        slot0[(quad * 4 + r) * 40 + ln] = f2bf(o[0][r] * inv[r]);
        slot0[(quad * 4 + r) * 40 + 16 + ln] = f2bf(o[1][r] * inv[r]);
        slot1[(quad * 4 + r) * 40 + ln] = f2bf(o[2][r] * inv[r]);
        slot1[(quad * 4 + r) * 40 + 16 + ln] = f2bf(o[3][r] * inv[r]);
      }
      LDS_FENCE();
      const short8 a0 = *reinterpret_cast<const short8*>(slot0 + ln * 40 + quad * 8);
      const short8 a1 = *reinterpret_cast<const short8*>(slot1 + ln * 40 + quad * 8);
      LDS_FENCE();

      // dense: O @ Wd; br0 parks in d_out (L3-absorbed), br1 fused epilogue
#pragma unroll
      for (int nt = 0; nt < 4; ++nt) {
        const short8 w0 = *reinterpret_cast<const short8*>(Wdsw + quad * 512 + (nt * 16 + ln) * 8);
        const short8 w1 =
            *reinterpret_cast<const short8*>(Wdsw + (4 + quad) * 512 + (nt * 16 + ln) * 8);
        float4v d4 = {0.f, 0.f, 0.f, 0.f};
        d4 = MFMA16(a0, w0, d4);
        d4 = MFMA16(a1, w1, d4);
        const int m0 = qt * 16 + quad * 4;
        const int col = nt * 16 + ln;
        if (br == 0) {
#pragma unroll
          for (int r = 0; r < 4; ++r) outb[(m0 + r) * 64 + col] = d4[r];
        } else {
#pragma unroll
          for (int r = 0; r < 4; ++r) {
            const float z = outb[(m0 + r) * 64 + col] + d4[r] + bdsum[nt];
            const float e = __builtin_amdgcn_exp2f(-z * kLog2e);
            const float gate = __builtin_amdgcn_rcpf(1.0f + e);
            outb[(m0 + r) * 64 + col] = xb[(m0 + r) * 64 + col] * gate;
          }
        }
      }
    }
    __syncthreads();  // protect LDS (R slots / Ksw / Vsw) before next branch restages
  }
}

extern "C" void kernel_launch(void* const* d_in, const int* in_sizes, int n_in,
                              void* d_out, int out_size, void* d_ws, size_t ws_size,
                              hipStream_t stream) {
  const float* x = (const float*)d_in[0];
  const float* Wq_t = (const float*)d_in[1];
  const float* Wk_t = (const float*)d_in[2];
  const float* Wv_t = (const float*)d_in[3];
  const float* Wq_s = (const float*)d_in[4];
  const float* Wk_s = (const float*)d_in[5];
  const float* Wv_s = (const float*)d_in[6];
  const float* Wd_t = (const float*)d_in[7];
  const float* bd_t = (const float*)d_in[8];
  const float* Wd_s = (const float*)d_in[9];
  const float* bd_s = (const float*)d_in[10];
  float* out = (float*)d_out;

  hipFuncSetAttribute(reinterpret_cast<const void*>(ts_attn_fused),
                      hipFuncAttributeMaxDynamicSharedMemorySize, LDS_TOTAL_BYTES);
  ts_attn_fused<<<dim3(256), dim3(kThreads), LDS_TOTAL_BYTES, stream>>>(
      x, Wq_t, Wk_t, Wv_t, Wq_s, Wk_s, Wv_s, Wd_t, bd_t, Wd_s, bd_s, out);
}